// Round 6
// baseline (28.287 us; speedup 1.0000x reference)
//
#include <hip/hip_runtime.h>

#define B_ 32
#define X_ 128
#define Y_ 256
#define C_ 64
#define BDIM 256
#define NITEM 8
#define NBLK  (B_ * X_ / NITEM)   /* 512 blocks -> 2/CU, all resident */
#define MIN_VALF -4294967295.0f

// Insert v into descending sorted triple (m1 >= m2 >= m3), keeping top-3.
__device__ __forceinline__ void insert3(float& m1, float& m2, float& m3, float v) {
    float hi1 = fmaxf(m1, v);
    float lo1 = fminf(m1, v);
    m1 = hi1;
    float hi2 = fmaxf(m2, lo1);
    float lo2 = fminf(m2, lo1);
    m2 = hi2;
    m3 = fmaxf(m3, lo2);
}

struct St {
    int   w;
    int   ylen;
    float inv_len;
    float xm;
    bool  alive;   // xm != 0
    bool  loads;   // alive && this wave's y-chunk non-empty
};

// Compute item state and issue its 16 row-loads (one burst, clamped rows).
__device__ __forceinline__ void issue_item(
    int g, int wv, int yofs, int c0,
    const float* __restrict__ inp, const float* __restrict__ xmask,
    const float* __restrict__ ylen_lds,
    St& st, float4 (&buf)[16])
{
    const int w = (g * 1997) & (B_ * X_ - 1);   // bijective scatter
    const int b = w >> 7;
    const int x = w & (X_ - 1);
    st.w  = w;
    st.xm = xmask[b * X_ + x];
    const float yf = ylen_lds[b];
    st.ylen    = (int)(yf + 0.5f);
    st.inv_len = 1.0f / yf;                      // ylen >= 4 per setup
    st.alive   = (st.xm != 0.0f);
    st.loads   = st.alive && (wv * 64 < st.ylen);
    if (st.loads) {
        const float* base = inp + ((size_t)w << 14) + c0;   // w * Y_*C_
        const int y0     = wv * 64 + yofs;
        const int yc_max = st.ylen - 1;
        #pragma unroll
        for (int i = 0; i < 16; ++i) {
            const int yr = y0 + 4 * i;
            const int yc = (yr < st.ylen) ? yr : yc_max;
            buf[i] = *reinterpret_cast<const float4*>(base + ((size_t)yc << 6));
        }
    }
}

// Consume the buffered rows: masked accumulate, in-wave merge, LDS stage.
__device__ __forceinline__ void consume_item(
    const St& st, int wv, int yofs, int lane,
    float4 (&buf)[16], float* ldsp)
{
    float m1[4], m2[4], m3[4], s[4];
    #pragma unroll
    for (int j = 0; j < 4; ++j) {
        m1[j] = MIN_VALF; m2[j] = MIN_VALF; m3[j] = MIN_VALF; s[j] = 0.0f;
    }

    if (st.loads) {
        const int y0 = wv * 64 + yofs;
        #pragma unroll
        for (int i = 0; i < 16; ++i) {
            const bool live = (y0 + 4 * i) < st.ylen;
            float vv[4] = {buf[i].x, buf[i].y, buf[i].z, buf[i].w};
            #pragma unroll
            for (int j = 0; j < 4; ++j) {
                s[j] += live ? vv[j] : 0.0f;
                insert3(m1[j], m2[j], m3[j], live ? vv[j] : MIN_VALF);
            }
        }
    }
    if (st.alive) {
        #pragma unroll
        for (int step = 0; step < 2; ++step) {
            const int msk = 16 << step;
            #pragma unroll
            for (int j = 0; j < 4; ++j) {
                float o1 = __shfl_xor(m1[j], msk);
                float o2 = __shfl_xor(m2[j], msk);
                float o3 = __shfl_xor(m3[j], msk);
                float os = __shfl_xor(s[j],  msk);
                s[j] += os;
                insert3(m1[j], m2[j], m3[j], o1);
                insert3(m1[j], m2[j], m3[j], o2);
                insert3(m1[j], m2[j], m3[j], o3);
            }
        }
        if (yofs == 0) {
            float* dst = ldsp + (wv * 16 + (lane & 15)) * 16;
            *reinterpret_cast<float4*>(dst +  0) = make_float4(m1[0], m1[1], m1[2], m1[3]);
            *reinterpret_cast<float4*>(dst +  4) = make_float4(m2[0], m2[1], m2[2], m2[3]);
            *reinterpret_cast<float4*>(dst +  8) = make_float4(m3[0], m3[1], m3[2], m3[3]);
            *reinterpret_cast<float4*>(dst + 12) = make_float4(s[0],  s[1],  s[2],  s[3]);
        }
    }
}

// Wave 0 only: merge the 4 chunk-partials from LDS and write the 3 outputs.
__device__ __forceinline__ void finalize_item(
    const St st, int lane, const float* ldsp, float* __restrict__ out)
{
    float* orow = out + (size_t)st.w * (3 * C_);
    if (!st.alive) {
        orow[lane] = 0.0f; orow[64 + lane] = 0.0f; orow[128 + lane] = 0.0f;
        return;
    }
    const int lg = lane >> 2, e = lane & 3;
    float M1 = MIN_VALF, M2 = MIN_VALF, M3 = MIN_VALF, S = 0.0f;
    #pragma unroll
    for (int q = 0; q < 4; ++q) {
        const float* src = ldsp + (q * 16 + lg) * 16;
        float a = src[e], bb = src[4 + e], c = src[8 + e], d = src[12 + e];
        S += d;
        insert3(M1, M2, M3, a);
        insert3(M1, M2, M3, bb);
        insert3(M1, M2, M3, c);
    }
    const float mean = S * st.inv_len;
    orow[lane]       = M1 * st.xm;
    orow[64 + lane]  = ((st.ylen >= 3) ? (M1 + M2 + M3) * (1.0f / 3.0f) : mean) * st.xm;
    orow[128 + lane] = mean;   // mean_pool is NOT x-masked in ref
}

__global__ __launch_bounds__(BDIM) void topk_pool_kernel(
    const float* __restrict__ inp,
    const float* __restrict__ xmask,
    const float* __restrict__ ymask,
    float* __restrict__ out)
{
    const int tid  = threadIdx.x;
    const int lane = tid & 63;
    const int wv   = tid >> 6;
    const int c0   = (lane & 15) << 2;
    const int yofs = lane >> 4;

    __shared__ float ylen_lds[B_];
    __shared__ float yps[8][B_];
    __shared__ float lds0[4 * 16 * 16];
    __shared__ float lds1[4 * 16 * 16];

    // Precompute ylen for all 32 batches once per block (ymask is L2-hot).
    {
        const int bq = tid & 31, seg = tid >> 5;
        const float4* yv = reinterpret_cast<const float4*>(ymask + bq * Y_ + seg * 32);
        float ps = 0.0f;
        #pragma unroll
        for (int k = 0; k < 8; ++k) { float4 q = yv[k]; ps += q.x + q.y + q.z + q.w; }
        yps[seg][bq] = ps;
    }
    __syncthreads();
    if (tid < B_) {
        float sacc = 0.0f;
        #pragma unroll
        for (int k = 0; k < 8; ++k) sacc += yps[k][tid];
        ylen_lds[tid] = sacc;
    }
    __syncthreads();

    const int g0 = blockIdx.x * NITEM;
    St stA, stB;
    float4 bufA[16], bufB[16];
    issue_item(g0 + 0, wv, yofs, c0, inp, xmask, ylen_lds, stA, bufA);
    issue_item(g0 + 1, wv, yofs, c0, inp, xmask, ylen_lds, stB, bufB);

    // Depth-2 software pipeline: while consuming item i, item i+1's loads are
    // in flight; item i+2 is issued the moment buffer A/B frees.
    for (int i = 0; i < NITEM; i += 2) {
        consume_item(stA, wv, yofs, lane, bufA, lds0);
        St snapA = stA;
        if (i + 2 < NITEM)
            issue_item(g0 + i + 2, wv, yofs, c0, inp, xmask, ylen_lds, stA, bufA);
        __syncthreads();
        if (wv == 0) finalize_item(snapA, lane, lds0, out);

        consume_item(stB, wv, yofs, lane, bufB, lds1);
        St snapB = stB;
        if (i + 3 < NITEM)
            issue_item(g0 + i + 3, wv, yofs, c0, inp, xmask, ylen_lds, stB, bufB);
        __syncthreads();
        if (wv == 0) finalize_item(snapB, lane, lds1, out);
    }
}

extern "C" void kernel_launch(void* const* d_in, const int* in_sizes, int n_in,
                              void* d_out, int out_size, void* d_ws, size_t ws_size,
                              hipStream_t stream) {
    const float* inp   = (const float*)d_in[0];
    const float* xmask = (const float*)d_in[1];
    const float* ymask = (const float*)d_in[2];
    float* out = (float*)d_out;

    topk_pool_kernel<<<NBLK, BDIM, 0, stream>>>(inp, xmask, ymask, out);
}

// Round 7
// 20.628 us; speedup vs baseline: 1.3713x; 1.3713x over previous
//
#include <hip/hip_runtime.h>

#define B_ 32
#define X_ 128
#define Y_ 256
#define C_ 64
#define BDIM 256
#define MIN_VALF -4294967295.0f

// Insert v into descending sorted triple (m1 >= m2 >= m3), keeping top-3.
__device__ __forceinline__ void insert3(float& m1, float& m2, float& m3, float v) {
    float hi1 = fmaxf(m1, v);
    float lo1 = fminf(m1, v);
    m1 = hi1;
    float hi2 = fmaxf(m2, lo1);
    float lo2 = fminf(m2, lo1);
    m2 = hi2;
    m3 = fmaxf(m3, lo2);
}

// One block per (b,x), 4 waves each owning a 64-row y-chunk, one 16-load
// burst per wave. vs R4: xmask AND ymask are issued together in the first
// memory trip (the dead-block branch waits only on xmask; ymask is already
// in flight for the live path) — startup drops from 3 serial round trips
// to 2.
__global__ __launch_bounds__(BDIM) void topk_pool_kernel(
    const float* __restrict__ inp,
    const float* __restrict__ xmask,
    const float* __restrict__ ymask,
    float* __restrict__ out)
{
    const int tid  = threadIdx.x;
    const int lane = tid & 63;
    const int wv   = tid >> 6;                      // wave id = y-chunk, 0..3

    // Bijective scatter of block -> (b,x) to mix long/short blocks across CUs.
    const int w = (blockIdx.x * 1997) & (B_ * X_ - 1);
    const int b = w >> 7;
    const int x = w & (X_ - 1);

    __shared__ float lds[4 * 16 * 16];              // [wave][chgrp][16 floats]

    // ---- trip 1: xmask + ymask issued together ----
    const float xm = xmask[b * X_ + x];
    const float* ym = ymask + b * Y_;
    const float y0v = ym[lane];
    const float y1v = ym[lane + 64];
    const float y2v = ym[lane + 128];
    const float y3v = ym[lane + 192];

    float* orow = out + (size_t)w * (3 * C_);

    if (xm == 0.0f) {                               // waits only on xmask
        if (wv == 0) {
            orow[lane]       = 0.0f;
            orow[64 + lane]  = 0.0f;
            orow[128 + lane] = 0.0f;
        }
        return;                                     // ALL waves return: no sync hazard
    }

    // ylen reduce (ymask values already arrived / arriving).
    float ysum = y0v + y1v + y2v + y3v;
    #pragma unroll
    for (int off = 32; off > 0; off >>= 1) ysum += __shfl_xor(ysum, off);
    const int   ylen    = (int)(ysum + 0.5f);
    const float inv_len = 1.0f / ysum;              // ylen >= 4 per setup

    const int c0   = (lane & 15) << 2;              // channel base (float4)
    const int yofs = lane >> 4;                     // y-subgroup 0..3

    float m1[4], m2[4], m3[4], s[4];
    #pragma unroll
    for (int j = 0; j < 4; ++j) {
        m1[j] = MIN_VALF; m2[j] = MIN_VALF; m3[j] = MIN_VALF; s[j] = 0.0f;
    }

    const float* base = inp + (size_t)(b * X_ + x) * (Y_ * C_) + c0;
    const int y_lo = wv * 64;
    const int y0   = y_lo + yofs;

    if (y_lo < ylen) {
        if (y_lo + 64 <= ylen) {
            // Full chunk: 16 independent loads in one batch, then consume.
            float4 v[16];
            #pragma unroll
            for (int i = 0; i < 16; ++i)
                v[i] = *reinterpret_cast<const float4*>(base + (size_t)(y0 + 4 * i) * C_);
            #pragma unroll
            for (int i = 0; i < 16; ++i) {
                float vv[4] = {v[i].x, v[i].y, v[i].z, v[i].w};
                #pragma unroll
                for (int j = 0; j < 4; ++j) {
                    s[j] += vv[j];
                    insert3(m1[j], m2[j], m3[j], vv[j]);
                }
            }
        } else {
            // Partial chunk: clamped row index (always valid), masked consume.
            float4 v[16];
            #pragma unroll
            for (int i = 0; i < 16; ++i) {
                const int yr = y0 + 4 * i;
                const int yc = (yr < ylen) ? yr : (ylen - 1);
                v[i] = *reinterpret_cast<const float4*>(base + (size_t)yc * C_);
            }
            #pragma unroll
            for (int i = 0; i < 16; ++i) {
                const bool live = (y0 + 4 * i) < ylen;
                float vv[4] = {v[i].x, v[i].y, v[i].z, v[i].w};
                #pragma unroll
                for (int j = 0; j < 4; ++j) {
                    const float vs = live ? vv[j] : 0.0f;
                    const float vt = live ? vv[j] : MIN_VALF;
                    s[j] += vs;
                    insert3(m1[j], m2[j], m3[j], vt);
                }
            }
        }
    }
    // (Waves with y_lo >= ylen keep init values — merge-neutral.)

    // In-wave merge of the 4 y-subgroups.
    #pragma unroll
    for (int step = 0; step < 2; ++step) {
        const int msk = 16 << step;
        #pragma unroll
        for (int j = 0; j < 4; ++j) {
            float o1 = __shfl_xor(m1[j], msk);
            float o2 = __shfl_xor(m2[j], msk);
            float o3 = __shfl_xor(m3[j], msk);
            float os = __shfl_xor(s[j],  msk);
            s[j] += os;
            insert3(m1[j], m2[j], m3[j], o1);
            insert3(m1[j], m2[j], m3[j], o2);
            insert3(m1[j], m2[j], m3[j], o3);
        }
    }

    // Stage per-wave partials: lds[wv][chgrp][m1[0..3] m2[0..3] m3[0..3] s[0..3]]
    if (yofs == 0) {
        float* dst = &lds[(wv * 16 + (lane & 15)) * 16];
        *reinterpret_cast<float4*>(dst +  0) = make_float4(m1[0], m1[1], m1[2], m1[3]);
        *reinterpret_cast<float4*>(dst +  4) = make_float4(m2[0], m2[1], m2[2], m2[3]);
        *reinterpret_cast<float4*>(dst +  8) = make_float4(m3[0], m3[1], m3[2], m3[3]);
        *reinterpret_cast<float4*>(dst + 12) = make_float4(s[0],  s[1],  s[2],  s[3]);
    }
    __syncthreads();

    // Wave 0 merges the 4 chunk-partials; lane == channel.
    if (wv == 0) {
        const int ch = lane, lg = ch >> 2, e = ch & 3;
        float M1 = MIN_VALF, M2 = MIN_VALF, M3 = MIN_VALF, S = 0.0f;
        #pragma unroll
        for (int q = 0; q < 4; ++q) {
            const float* src = &lds[(q * 16 + lg) * 16];
            float a = src[e], bb = src[4 + e], c = src[8 + e], d = src[12 + e];
            S += d;
            insert3(M1, M2, M3, a);
            insert3(M1, M2, M3, bb);
            insert3(M1, M2, M3, c);
        }
        const float mean = S * inv_len;
        const float top1 = M1 * xm;
        const float top3 = ((ylen >= 3) ? (M1 + M2 + M3) * (1.0f / 3.0f) : mean) * xm;
        orow[ch]       = top1;
        orow[64 + ch]  = top3;
        orow[128 + ch] = mean;          // mean_pool is NOT x-masked in ref
    }
}

extern "C" void kernel_launch(void* const* d_in, const int* in_sizes, int n_in,
                              void* d_out, int out_size, void* d_ws, size_t ws_size,
                              hipStream_t stream) {
    const float* inp   = (const float*)d_in[0];
    const float* xmask = (const float*)d_in[1];
    const float* ymask = (const float*)d_in[2];
    float* out = (float*)d_out;

    const int grid = B_ * X_;           // one block per (b,x)
    topk_pool_kernel<<<grid, BDIM, 0, stream>>>(inp, xmask, ymask, out);
}